// Round 7
// baseline (1752.624 us; speedup 1.0000x reference)
//
#include <hip/hip_runtime.h>
#include <stdint.h>

#define BB 256
#define NN 2048
#define NCORE 8
#define TSIM 32
#define NSTEP 39
#define PLANE_E (BB*NN)        // 524288 elements
#define PLANE_I PLANE_E        // 512 KiB i8 plane
#define AROWB 2048             // bytes per i8 row

typedef int i4v __attribute__((ext_vector_type(4)));

__device__ __forceinline__ void load_lds16(const void* g, void* l) {
  __builtin_amdgcn_global_load_lds((const __attribute__((address_space(1))) void*)g,
                                   (__attribute__((address_space(3))) void*)l, 16, 0, 0);
}

// ---------------- zero init ----------------
__global__ void zero_f32_kernel(float* __restrict__ p, int n4) {
  int i = blockIdx.x * 256 + threadIdx.x;
  if (i < n4) ((float4*)p)[i] = make_float4(0.f, 0.f, 0.f, 0.f);
}

// ---------------- spike trains, i8 {0,1}, swizzled A layout ----------------
// byte(b,k) = b*2048 + (k>>7)*128 + ((((k>>4)&7) ^ (b&7))<<4) + (k&15)
// grid (128, 8): blockIdx.y = cycle quad (8x parallel vs round 6)
__global__ void spikes_kernel(const float* __restrict__ x, uint8_t* __restrict__ strain) {
  int gid = blockIdx.x * 256 + threadIdx.x;   // over BB*NN/16 = 32768
  int b = gid >> 7, kg = gid & 127;           // kg = 16-elem k-group
  const float* xp = x + (size_t)b * NN + kg * 16;
  float nsf[16], sp[16]; int ns[16];
#pragma unroll
  for (int e = 0; e < 16; ++e) {
    float nv = rintf(xp[e] * 32.0f);
    nsf[e] = nv; ns[e] = (int)nv; sp[e] = 32.0f / fmaxf(nv, 1.0f);
  }
  uint32_t dst = (uint32_t)b * 2048 + ((uint32_t)(kg >> 3) << 7)
               + ((uint32_t)((kg & 7) ^ (b & 7)) << 4);
  int cyc0 = blockIdx.y * 4;
#pragma unroll
  for (int i = 0; i < 4; ++i) {
    int cyc = cyc0 + i;
    float ct = (float)cyc;
    uint32_t w[4] = {0u, 0u, 0u, 0u};
#pragma unroll
    for (int e = 0; e < 16; ++e) {
      bool res;
      if (ns[e] == TSIM)      res = true;
      else if (ns[e] == 0)    res = false;
      else {
        float q = floorf(ct / sp[e]);
        float m = fmodf(ct, sp[e]);
        res = (q < nsf[e]) && (floorf(m) == 0.0f);
      }
      if (res) w[e >> 2] |= 1u << ((e & 3) * 8);
    }
    uint4 pk; pk.x = w[0]; pk.y = w[1]; pk.z = w[2]; pk.w = w[3];
    *(uint4*)(strain + (size_t)cyc * PLANE_I + dst) = pk;
  }
}

// ---------------- W split: exact i8 3-plane fixed point, REG-FRAGMENT layout ----------------
// Whm region per (c, nt64) = 16 chunks * 24576 B.  Chunk kk flat group
// idx = (((ks2*3+p)*2+nj)*2+wn)*64 + lane ; 16 B content: plane p,
// n = nt64*64 + wn*32 + nj*16 + (lane&15), k = kk*128 + ks2*64 + (lane>>4)*16 + e.
__global__ __launch_bounds__(256) void wsplit_kernel(const float* __restrict__ W,
                                                     uint8_t* __restrict__ Whm) {
  __shared__ uint32_t lds[3 * 2048];   // [p][kq(32)][n(64)] u32 (4 k-bytes)
  int kk = blockIdx.x, nt = blockIdx.y, c = blockIdx.z;
  int tid = threadIdx.x, lane = tid & 63, wid = tid >> 6;
  const float* src = W + ((size_t)c * NN + (size_t)kk * 128) * NN + nt * 64 + lane;
#pragma unroll
  for (int kp = 0; kp < 8; ++kp) {
    uint32_t pk0 = 0, pk1 = 0, pk2 = 0;
#pragma unroll
    for (int q = 0; q < 4; ++q) {
      int kl = kp * 16 + wid * 4 + q;
      float w = src[(size_t)kl * NN];
      int wi = (int)rintf(w * 0x1p25f);            // exact: |wi| < 2^22
      int l8 = (int)(int8_t)(uint8_t)(wi & 0xFF);
      int r1 = (wi - l8) >> 8;
      int m8 = (int)(int8_t)(uint8_t)(r1 & 0xFF);
      int h8 = (r1 - m8) >> 8;
      pk0 |= ((uint32_t)(uint8_t)h8) << (q * 8);
      pk1 |= ((uint32_t)(uint8_t)m8) << (q * 8);
      pk2 |= ((uint32_t)(uint8_t)l8) << (q * 8);
    }
    int kq = kp * 4 + wid;
    lds[0 * 2048 + kq * 64 + lane] = pk0;
    lds[1 * 2048 + kq * 64 + lane] = pk1;
    lds[2 * 2048 + kq * 64 + lane] = pk2;
  }
  __syncthreads();
  size_t chunkbase = (((size_t)c * 32 + nt) * 16 + kk) * 24576;
#pragma unroll
  for (int g = 0; g < 6; ++g) {
    int idx = g * 256 + tid;
    int lane6 = idx & 63;
    int t2 = idx >> 6;
    int wn = t2 & 1, nj = (t2 >> 1) & 1;
    int t3 = idx >> 8;                 // ks2*3 + p
    int pp = t3 % 3, ks2 = t3 / 3;
    int n = wn * 32 + nj * 16 + (lane6 & 15);
    int kqb = ks2 * 16 + (lane6 >> 4) * 4;
    uint4 v;
    v.x = lds[pp * 2048 + (kqb + 0) * 64 + n];
    v.y = lds[pp * 2048 + (kqb + 1) * 64 + n];
    v.z = lds[pp * 2048 + (kqb + 2) * 64 + n];
    v.w = lds[pp * 2048 + (kqb + 3) * 64 + n];
    *(uint4*)(Whm + chunkbase + (size_t)idx * 16) = v;
  }
}

// ---------------- one pipeline step: 8 waves, BK=128, B-in-registers ----------------
// grid (active cores, 2048/BN n-tiles), 512 threads.
template<int BN>
__global__ __launch_bounds__(512, 2) void step_kernel(
    const uint8_t* __restrict__ Whm, const float* __restrict__ thresholds,
    const uint8_t* __restrict__ strain,
    const uint8_t* __restrict__ buf_prev, uint8_t* __restrict__ buf_cur,
    float* __restrict__ memb, float* __restrict__ out, int t, int c_lo) {
  constexpr int MI   = (BN == 64) ? 4 : 2;     // 16-row frags per wave
  constexpr int CLST = (BN == 64) ? 68 : 36;
  __shared__ uint8_t smem[65536];              // A double buffer only

  const int tid = threadIdx.x;
  const int c  = c_lo + blockIdx.x;
  const int nt = blockIdx.y;
  const int l = tid & 63, wid = tid >> 6;
  const int wm = (BN == 64) ? (wid >> 1) : wid;
  const int wn = (BN == 64) ? (wid & 1) : (nt & 1);
  const int lr = l & 15, lh = l >> 4;

  const uint8_t* Asrc = (c == 0) ? (strain + (size_t)t * PLANE_I)
                                 : (buf_prev + (size_t)(c - 1) * PLANE_I);
  const uint8_t* ab[4];
#pragma unroll
  for (int j = 0; j < 4; ++j) {
    int i = j * 512 + tid;
    ab[j] = Asrc + (size_t)(i >> 3) * AROWB + (i & 7) * 16;
  }
  const int nt64 = (BN == 64) ? nt : (nt >> 1);
  const uint8_t* bsrc = Whm + (((size_t)c * 32 + nt64) * 16) * 24576
                      + (size_t)wn * 1024 + (size_t)l * 16;

  // A fragment LDS offset (rows 128 B, 3-bit slot swizzle; ks2 toggles bit 6)
  const uint32_t base_aoff = (uint32_t)(wm * (MI * 16) + lr) * 128
                           + ((uint32_t)(lh ^ (lr & 7)) << 4);

  i4v acc[3][MI][2];
  const i4v izero = {0, 0, 0, 0};
#pragma unroll
  for (int p = 0; p < 3; ++p)
#pragma unroll
    for (int mi = 0; mi < MI; ++mi) { acc[p][mi][0] = izero; acc[p][mi][1] = izero; }

  i4v bA[12], bB[12];

#define ISSA(kk, slot) do { \
    uint8_t* Ad_ = smem + (slot) * 32768; \
    _Pragma("unroll") \
    for (int j_ = 0; j_ < 4; ++j_) \
      load_lds16(ab[j_] + (kk) * 128, Ad_ + (j_ * 512 + tid) * 16); \
  } while (0)

#define LOADB(dst, kk) do { \
    const uint8_t* bp_ = bsrc + (size_t)(kk) * 24576; \
    _Pragma("unroll") \
    for (int j_ = 0; j_ < 12; ++j_) \
      dst[j_] = *(const i4v*)(bp_ + j_ * 2048); \
  } while (0)

#define COMP(slot, br) do { \
    const uint8_t* Ab_ = smem + (slot) * 32768; \
    __builtin_amdgcn_s_setprio(1); \
    _Pragma("unroll") \
    for (int ks_ = 0; ks_ < 2; ++ks_) { \
      _Pragma("unroll") \
      for (int mi_ = 0; mi_ < MI; ++mi_) { \
        i4v a_ = *(const i4v*)(Ab_ + (base_aoff ^ (ks_ << 6)) + mi_ * 2048); \
        _Pragma("unroll") \
        for (int p_ = 0; p_ < 3; ++p_) { \
          acc[p_][mi_][0] = __builtin_amdgcn_mfma_i32_16x16x64_i8(a_, br[(ks_ * 3 + p_) * 2 + 0], acc[p_][mi_][0], 0, 0, 0); \
          acc[p_][mi_][1] = __builtin_amdgcn_mfma_i32_16x16x64_i8(a_, br[(ks_ * 3 + p_) * 2 + 1], acc[p_][mi_][1], 0, 0, 0); \
        } \
      } \
    } \
    __builtin_amdgcn_s_setprio(0); \
  } while (0)

#define WAITV(n) asm volatile("s_waitcnt vmcnt(" #n ")" ::: "memory")
#define WAITL() asm volatile("s_waitcnt lgkmcnt(0)" ::: "memory")
#define BAR() do { __builtin_amdgcn_s_barrier(); __builtin_amdgcn_sched_barrier(0); } while (0)

  ISSA(0, 0); LOADB(bA, 0);
#pragma unroll 1
  for (int kp = 0; kp < 8; ++kp) {
    int k0 = kp * 2;
    // even phase: prefetch k0+1, compute k0 (bA, slot 0)
    ISSA(k0 + 1, 1); LOADB(bB, k0 + 1);
    WAITV(16);                 // retires batch k0 (4 DMA + 12 B-loads)
    BAR();
    COMP(0, bA);
    WAITL(); BAR();
    // odd phase: prefetch k0+2, compute k0+1 (bB, slot 1)
    if (k0 + 2 < 16) { ISSA(k0 + 2, 0); LOADB(bA, k0 + 2); WAITV(16); }
    else             { WAITV(0); }
    BAR();
    COMP(1, bB);
    WAITL(); BAR();
  }
#undef ISSA
#undef LOADB
#undef COMP
#undef WAITV
#undef WAITL
#undef BAR

  // ---- epilogue: exact i32 recombine -> float, LDS transpose, membrane update ----
  __syncthreads();
  const float thr = thresholds[c];
  float* Cl = (float*)smem;
  const int o0 = nt * BN;
  float* membp = memb + (size_t)c * PLANE_E;
  uint8_t* bufc = buf_cur + (size_t)c * PLANE_I;
  const bool last = (t == NSTEP - 1);
  constexpr int NH = (BN == 64) ? 2 : 1;
#pragma unroll
  for (int h = 0; h < NH; ++h) {
    if (h) __syncthreads();
    if (BN == 32 || (wm >> 1) == h) {
#pragma unroll
      for (int mi = 0; mi < MI; ++mi)
#pragma unroll
        for (int nj = 0; nj < 2; ++nj)
#pragma unroll
          for (int rg = 0; rg < 4; ++rg) {
            int row = wm * (MI * 16) + mi * 16 + lh * 4 + rg - h * 128;
            int col = ((BN == 64) ? wn * 32 : 0) + nj * 16 + lr;
            int di = (acc[0][mi][nj][rg] << 16) + (acc[1][mi][nj][rg] << 8)
                   + acc[2][mi][nj][rg];
            Cl[row * CLST + col] = (float)di * 0x1p-25f;  // single RNE rounding
          }
    }
    __syncthreads();
#pragma unroll
    for (int p = 0; p < 4; ++p) {
      int rr, c4;
      if constexpr (BN == 64) { rr = p * 32 + (tid >> 4); c4 = (tid & 15) * 4; }
      else                    { rr = p * 64 + (tid >> 3); c4 = (tid & 7) * 4; }
      int b = h * 128 + rr;
      int o = o0 + c4;
      float4 d = *(const float4*)&Cl[rr * CLST + c4];
      size_t idx = (size_t)b * NN + o;
      float4 mvv = *(float4*)(membp + idx);
      mvv.x += d.x; mvv.y += d.y; mvv.z += d.z; mvv.w += d.w;
      bool g0 = thr < mvv.x, g1 = thr < mvv.y, g2 = thr < mvv.z, g3 = thr < mvv.w;
      if (g0) mvv.x -= thr;  if (g1) mvv.y -= thr;
      if (g2) mvv.z -= thr;  if (g3) mvv.w -= thr;
      *(float4*)(membp + idx) = mvv;
      uint32_t ba = (uint32_t)b * AROWB + ((uint32_t)(o >> 7) << 7)
                  + ((uint32_t)(((o >> 4) & 7) ^ (b & 7)) << 4) + (o & 15);
      uchar4 pk;
      pk.x = g0 ? 1 : 0; pk.y = g1 ? 1 : 0; pk.z = g2 ? 1 : 0; pk.w = g3 ? 1 : 0;
      *(uchar4*)(bufc + ba) = pk;
      if (c == NCORE - 1) {
        float4 cv = *(float4*)(out + idx);
        cv.x += g0 ? 1.f : 0.f; cv.y += g1 ? 1.f : 0.f;
        cv.z += g2 ? 1.f : 0.f; cv.w += g3 ? 1.f : 0.f;
        if (last) { cv.x *= 0.03125f; cv.y *= 0.03125f; cv.z *= 0.03125f; cv.w *= 0.03125f; }
        *(float4*)(out + idx) = cv;
      }
    }
  }
}

extern "C" void kernel_launch(void* const* d_in, const int* in_sizes, int n_in,
                              void* d_out, int out_size, void* d_ws, size_t ws_size,
                              hipStream_t stream) {
  const float* x   = (const float*)d_in[0];
  const float* W   = (const float*)d_in[1];
  const float* thr = (const float*)d_in[2];
  float* out = (float*)d_out;
  uint8_t* ws = (uint8_t*)d_ws;

  // layout: memb f32 16.78M | strain i8 16.78M | buf0 4.19M | buf1 4.19M | Whm 100.7M
  float*   memb   = (float*)ws;
  uint8_t* strain = ws + 16777216;
  uint8_t* buf0   = ws + 33554432;
  uint8_t* buf1   = ws + 37748736;
  uint8_t* Whm    = ws + 41943040;

  zero_f32_kernel<<<dim3(4096), 256, 0, stream>>>(memb, 1048576);
  zero_f32_kernel<<<dim3(512),  256, 0, stream>>>(out, 131072);
  spikes_kernel<<<dim3(128, 8), 256, 0, stream>>>(x, strain);
  wsplit_kernel<<<dim3(16, 32, 8), 256, 0, stream>>>(W, Whm);

  for (int t = 0; t < NSTEP; ++t) {
    int c_lo = (t > TSIM - 1) ? (t - (TSIM - 1)) : 0;
    int c_hi = (t < NCORE - 1) ? t : (NCORE - 1);
    int nc = c_hi - c_lo + 1;
    uint8_t* prev = (t & 1) ? buf0 : buf1;
    uint8_t* cur  = (t & 1) ? buf1 : buf0;
    if (nc <= 4) {
      step_kernel<32><<<dim3(nc, 64), 512, 0, stream>>>(
          Whm, thr, strain, prev, cur, memb, out, t, c_lo);
    } else {
      step_kernel<64><<<dim3(nc, 32), 512, 0, stream>>>(
          Whm, thr, strain, prev, cur, memb, out, t, c_lo);
    }
  }
}

// Round 8
// 1212.223 us; speedup vs baseline: 1.4458x; 1.4458x over previous
//
#include <hip/hip_runtime.h>
#include <stdint.h>

#define BB 256
#define NN 2048
#define NCORE 8
#define TSIM 32
#define NSTEP 39
#define PLANE_E (BB*NN)        // 524288 elements
#define PLANE_I PLANE_E        // 512 KiB i8 plane
#define AROWB 2048             // bytes per i8 row

typedef int i4v __attribute__((ext_vector_type(4)));

__device__ __forceinline__ void load_lds16(const void* g, void* l) {
  __builtin_amdgcn_global_load_lds((const __attribute__((address_space(1))) void*)g,
                                   (__attribute__((address_space(3))) void*)l, 16, 0, 0);
}

// ---------------- zero init ----------------
__global__ void zero_f32_kernel(float* __restrict__ p, int n4) {
  int i = blockIdx.x * 256 + threadIdx.x;
  if (i < n4) ((float4*)p)[i] = make_float4(0.f, 0.f, 0.f, 0.f);
}

// ---------------- spike trains, i8 {0,1}, swizzled A layout ----------------
// byte(b,k) = b*2048 + (k>>7)*128 + ((((k>>4)&7) ^ (b&7))<<4) + (k&15)
// grid (128, 8): blockIdx.y = cycle quad (8x parallel)
__global__ void spikes_kernel(const float* __restrict__ x, uint8_t* __restrict__ strain) {
  int gid = blockIdx.x * 256 + threadIdx.x;   // over BB*NN/16 = 32768
  int b = gid >> 7, kg = gid & 127;           // kg = 16-elem k-group
  const float* xp = x + (size_t)b * NN + kg * 16;
  float nsf[16], sp[16]; int ns[16];
#pragma unroll
  for (int e = 0; e < 16; ++e) {
    float nv = rintf(xp[e] * 32.0f);
    nsf[e] = nv; ns[e] = (int)nv; sp[e] = 32.0f / fmaxf(nv, 1.0f);
  }
  uint32_t dst = (uint32_t)b * 2048 + ((uint32_t)(kg >> 3) << 7)
               + ((uint32_t)((kg & 7) ^ (b & 7)) << 4);
  int cyc0 = blockIdx.y * 4;
#pragma unroll
  for (int i = 0; i < 4; ++i) {
    int cyc = cyc0 + i;
    float ct = (float)cyc;
    uint32_t w[4] = {0u, 0u, 0u, 0u};
#pragma unroll
    for (int e = 0; e < 16; ++e) {
      bool res;
      if (ns[e] == TSIM)      res = true;
      else if (ns[e] == 0)    res = false;
      else {
        float q = floorf(ct / sp[e]);
        float m = fmodf(ct, sp[e]);
        res = (q < nsf[e]) && (floorf(m) == 0.0f);
      }
      if (res) w[e >> 2] |= 1u << ((e & 3) * 8);
    }
    uint4 pk; pk.x = w[0]; pk.y = w[1]; pk.z = w[2]; pk.w = w[3];
    *(uint4*)(strain + (size_t)cyc * PLANE_I + dst) = pk;
  }
}

// ---------------- W split: exact i8 3-plane fixed point (wi = rint(w*2^25)) ----------------
// Whm chunk id = ((c*32 + nt)*16 + kk), 24576 B; group idx = ks2*768 + p*256 + n*4 + s,
// content = plane p bytes of k = kk*128 + ks2*64 + (s ^ ((n>>1)&3))*16 + 0..15, col n.
__global__ __launch_bounds__(256) void wsplit_kernel(const float* __restrict__ W,
                                                     uint8_t* __restrict__ Whm, int c) {
  __shared__ uint32_t lds[3 * 2048];   // [p][kq(32)][n(64)] u32 (4 k-bytes each)
  int kk = blockIdx.x, nt = blockIdx.y;
  int tid = threadIdx.x, lane = tid & 63, wid = tid >> 6;
  const float* src = W + ((size_t)c * NN + (size_t)kk * 128) * NN + nt * 64 + lane;
#pragma unroll
  for (int kp = 0; kp < 8; ++kp) {
    uint32_t pk0 = 0, pk1 = 0, pk2 = 0;
#pragma unroll
    for (int q = 0; q < 4; ++q) {
      int kl = kp * 16 + wid * 4 + q;
      float w = src[(size_t)kl * NN];
      int wi = (int)rintf(w * 0x1p25f);            // |wi| < 2^22
      int l8 = (int)(int8_t)(uint8_t)(wi & 0xFF);
      int r1 = (wi - l8) >> 8;
      int m8 = (int)(int8_t)(uint8_t)(r1 & 0xFF);
      int h8 = (r1 - m8) >> 8;                     // |h8| <= 64
      pk0 |= ((uint32_t)(uint8_t)h8) << (q * 8);
      pk1 |= ((uint32_t)(uint8_t)m8) << (q * 8);
      pk2 |= ((uint32_t)(uint8_t)l8) << (q * 8);
    }
    int kq = kp * 4 + wid;
    lds[0 * 2048 + kq * 64 + lane] = pk0;
    lds[1 * 2048 + kq * 64 + lane] = pk1;
    lds[2 * 2048 + kq * 64 + lane] = pk2;
  }
  __syncthreads();
  size_t chunkbase = (((size_t)c * 32 + nt) * 16 + kk) * 24576;
#pragma unroll
  for (int g = 0; g < 6; ++g) {
    int idx = g * 256 + tid;
    int ks2 = (idx >= 768) ? 1 : 0;
    int rem = idx - ks2 * 768;
    int p = rem >> 8;
    int n = (rem >> 2) & 63;
    int s = rem & 3;
    int k16 = s ^ ((n >> 1) & 3);
    int kqb = ks2 * 16 + k16 * 4;
    uint4 v;
    v.x = lds[p * 2048 + (kqb + 0) * 64 + n];
    v.y = lds[p * 2048 + (kqb + 1) * 64 + n];
    v.z = lds[p * 2048 + (kqb + 2) * 64 + n];
    v.w = lds[p * 2048 + (kqb + 3) * 64 + n];
    *(uint4*)(Whm + chunkbase + (size_t)idx * 16) = v;
  }
}

// ---------------- one pipeline step: 8 waves, BK=128, depth-2 counted pipeline ----------------
// grid (active cores, 2048/BN n-tiles), 512 threads.
template<int BN>
__global__ __launch_bounds__(512) void step_kernel(
    const uint8_t* __restrict__ Whm, const float* __restrict__ thresholds,
    const uint8_t* __restrict__ strain,
    const uint8_t* __restrict__ buf_prev, uint8_t* __restrict__ buf_cur,
    float* __restrict__ memb, float* __restrict__ out, int t, int c_lo) {
  constexpr int BCH = (BN == 64) ? 24576 : 12288;  // B bytes per BK=128 chunk
  constexpr int MI  = (BN == 64) ? 4 : 2;          // 16-row frags per wave
  constexpr int KS2 = (BN == 64) ? 12288 : 6144;   // ks2 stride in LDS B
  constexpr int PS  = (BN == 64) ? 4096 : 2048;    // plane stride in LDS B
  constexpr int CLST = BN + 4;
  __shared__ uint8_t smem[2 * 32768 + 2 * BCH];

  const int tid = threadIdx.x;
  const int c  = c_lo + blockIdx.x;
  const int nt = blockIdx.y;
  const int l = tid & 63, wid = tid >> 6;
  const int wm = (BN == 64) ? (wid >> 1) : wid;
  const int wn = (BN == 64) ? (wid & 1) : 0;
  const int lr = l & 15, lh = l >> 4;
  uint8_t* As = smem;
  uint8_t* Bs = smem + 2 * 32768;

  const uint8_t* Asrc = (c == 0) ? (strain + (size_t)t * PLANE_I)
                                 : (buf_prev + (size_t)(c - 1) * PLANE_I);
  const uint8_t* ab[4];
#pragma unroll
  for (int j = 0; j < 4; ++j) {
    int i = j * 512 + tid;
    ab[j] = Asrc + (size_t)(i >> 3) * AROWB + (i & 7) * 16;
  }
  const size_t wcb = (((size_t)c * 32 + ((BN == 64) ? nt : (nt >> 1))) * 16) * 24576;
  const uint8_t* bb[3];
  if constexpr (BN == 64) {
#pragma unroll
    for (int j = 0; j < 3; ++j) bb[j] = Whm + wcb + (size_t)(j * 512 + tid) * 16;
  } else {
    int t2 = tid & 255;
#pragma unroll
    for (int j = 0; j < 3; ++j) {
      int li = j * 256 + t2;
      int ks2 = (li >= 384) ? 1 : 0;
      int rm = li - ks2 * 384;
      int p = rm >> 7, q = rm & 127;
      bb[j] = Whm + wcb + (size_t)(ks2 * 768 + p * 256 + (nt & 1) * 128 + q) * 16;
    }
  }

  // fragment LDS byte offsets (A rows 128 B, 3-bit slot swizzle; ks toggles bit 6)
  const uint32_t base_aoff = (uint32_t)(wm * (MI * 16) + lr) * 128
                           + ((uint32_t)(lh ^ (lr & 7)) << 4);
  uint32_t bo[2];
#pragma unroll
  for (int nj = 0; nj < 2; ++nj) {
    int n = wn * 32 + nj * 16 + lr;
    bo[nj] = (uint32_t)n * 64 + ((uint32_t)(lh ^ ((n >> 1) & 3)) << 4);
  }

  i4v acc[3][MI][2];
  const i4v izero = {0, 0, 0, 0};
#pragma unroll
  for (int p = 0; p < 3; ++p)
#pragma unroll
    for (int mi = 0; mi < MI; ++mi) { acc[p][mi][0] = izero; acc[p][mi][1] = izero; }

  auto issue = [&](int kk, int slot) {
    uint8_t* Ad = As + slot * 32768;
    uint8_t* Bd = Bs + slot * BCH;
#pragma unroll
    for (int j = 0; j < 4; ++j)
      load_lds16(ab[j] + kk * 128, Ad + (j * 512 + tid) * 16);
    if constexpr (BN == 64) {
#pragma unroll
      for (int j = 0; j < 3; ++j)
        load_lds16(bb[j] + (size_t)kk * 24576, Bd + (j * 512 + tid) * 16);
    } else {
      if (tid < 256) {
#pragma unroll
        for (int j = 0; j < 3; ++j)
          load_lds16(bb[j] + (size_t)kk * 24576, Bd + (j * 256 + (tid & 255)) * 16);
      }
    }
  };

  auto comp = [&](int slot) {
    const uint8_t* Ab = As + slot * 32768;
    const uint8_t* Bb = Bs + slot * BCH;
    __builtin_amdgcn_s_setprio(1);
#pragma unroll
    for (int ks = 0; ks < 2; ++ks) {
      i4v b00 = *(const i4v*)(Bb + ks * KS2 + 0 * PS + bo[0]);
      i4v b10 = *(const i4v*)(Bb + ks * KS2 + 1 * PS + bo[0]);
      i4v b20 = *(const i4v*)(Bb + ks * KS2 + 2 * PS + bo[0]);
      i4v b01 = *(const i4v*)(Bb + ks * KS2 + 0 * PS + bo[1]);
      i4v b11 = *(const i4v*)(Bb + ks * KS2 + 1 * PS + bo[1]);
      i4v b21 = *(const i4v*)(Bb + ks * KS2 + 2 * PS + bo[1]);
#pragma unroll
      for (int mi = 0; mi < MI; ++mi) {
        i4v a = *(const i4v*)(Ab + (base_aoff ^ (ks << 6)) + mi * 2048);
        acc[0][mi][0] = __builtin_amdgcn_mfma_i32_16x16x64_i8(a, b00, acc[0][mi][0], 0, 0, 0);
        acc[1][mi][0] = __builtin_amdgcn_mfma_i32_16x16x64_i8(a, b10, acc[1][mi][0], 0, 0, 0);
        acc[2][mi][0] = __builtin_amdgcn_mfma_i32_16x16x64_i8(a, b20, acc[2][mi][0], 0, 0, 0);
        acc[0][mi][1] = __builtin_amdgcn_mfma_i32_16x16x64_i8(a, b01, acc[0][mi][1], 0, 0, 0);
        acc[1][mi][1] = __builtin_amdgcn_mfma_i32_16x16x64_i8(a, b11, acc[1][mi][1], 0, 0, 0);
        acc[2][mi][1] = __builtin_amdgcn_mfma_i32_16x16x64_i8(a, b21, acc[2][mi][1], 0, 0, 0);
      }
    }
    __builtin_amdgcn_s_setprio(0);
  };

#define WAITV(n) asm volatile("s_waitcnt vmcnt(" #n ")" ::: "memory")
#define WAITL() asm volatile("s_waitcnt lgkmcnt(0)" ::: "memory")
#define BAR() do { __builtin_amdgcn_s_barrier(); __builtin_amdgcn_sched_barrier(0); } while (0)

  issue(0, 0);
  for (int k = 0; k < 16; ++k) {
    if (k < 15) {
      issue(k + 1, (k + 1) & 1);
      if constexpr (BN == 64) { WAITV(7); }
      else { if (wid < 4) { WAITV(7); } else { WAITV(4); } }
    } else {
      WAITV(0);
    }
    BAR();                     // chunk k landed for all waves
    comp(k & 1);
    WAITL();                   // this wave's ds_reads of slot k&1 complete
    BAR();                     // slot k&1 free to overwrite next iter
  }
#undef WAITV
#undef WAITL
#undef BAR

  // ---- epilogue: exact i32 recombine -> float, LDS transpose, membrane update ----
  __syncthreads();
  const float thr = thresholds[c];
  float* Cl = (float*)smem;
#pragma unroll
  for (int mi = 0; mi < MI; ++mi)
#pragma unroll
    for (int nj = 0; nj < 2; ++nj)
#pragma unroll
      for (int rg = 0; rg < 4; ++rg) {
        int row = wm * (MI * 16) + mi * 16 + lh * 4 + rg;
        int col = wn * 32 + nj * 16 + lr;
        int di = (acc[0][mi][nj][rg] << 16) + (acc[1][mi][nj][rg] << 8) + acc[2][mi][nj][rg];
        Cl[row * CLST + col] = (float)di * 0x1p-25f;   // single RNE rounding of exact sum
      }
  __syncthreads();

  const int o0 = nt * BN;
  float* membp = memb + (size_t)c * PLANE_E;
  uint8_t* bufc = buf_cur + (size_t)c * PLANE_I;
  const bool last = (t == NSTEP - 1);
  constexpr int NP = (BN == 64) ? 8 : 4;
#pragma unroll
  for (int p = 0; p < NP; ++p) {
    int rr, c4;
    if constexpr (BN == 64) { rr = p * 32 + (tid >> 4); c4 = (tid & 15) * 4; }
    else                    { rr = p * 64 + (tid >> 3); c4 = (tid & 7) * 4; }
    int o = o0 + c4;
    float4 d = *(const float4*)&Cl[rr * CLST + c4];
    size_t idx = (size_t)rr * NN + o;
    float4 mvv = *(float4*)(membp + idx);
    mvv.x += d.x; mvv.y += d.y; mvv.z += d.z; mvv.w += d.w;
    bool g0 = thr < mvv.x, g1 = thr < mvv.y, g2 = thr < mvv.z, g3 = thr < mvv.w;
    if (g0) mvv.x -= thr;  if (g1) mvv.y -= thr;
    if (g2) mvv.z -= thr;  if (g3) mvv.w -= thr;
    *(float4*)(membp + idx) = mvv;
    // i8 swizzled buf store: byte(b,k) = b*2048 + (k>>7)*128 + ((((k>>4)&7)^(b&7))<<4) + (k&15)
    uint32_t ba = (uint32_t)rr * AROWB + ((uint32_t)(o >> 7) << 7)
                + ((uint32_t)(((o >> 4) & 7) ^ (rr & 7)) << 4) + (o & 15);
    uchar4 pk;
    pk.x = g0 ? 1 : 0; pk.y = g1 ? 1 : 0; pk.z = g2 ? 1 : 0; pk.w = g3 ? 1 : 0;
    *(uchar4*)(bufc + ba) = pk;
    if (c == NCORE - 1) {
      float4 cv = *(float4*)(out + idx);
      cv.x += g0 ? 1.f : 0.f; cv.y += g1 ? 1.f : 0.f;
      cv.z += g2 ? 1.f : 0.f; cv.w += g3 ? 1.f : 0.f;
      if (last) { cv.x *= 0.03125f; cv.y *= 0.03125f; cv.z *= 0.03125f; cv.w *= 0.03125f; }
      *(float4*)(out + idx) = cv;
    }
  }
}

extern "C" void kernel_launch(void* const* d_in, const int* in_sizes, int n_in,
                              void* d_out, int out_size, void* d_ws, size_t ws_size,
                              hipStream_t stream) {
  const float* x   = (const float*)d_in[0];
  const float* W   = (const float*)d_in[1];
  const float* thr = (const float*)d_in[2];
  float* out = (float*)d_out;
  uint8_t* ws = (uint8_t*)d_ws;

  // layout: memb f32 16.78M | strain i8 16.78M | buf0 4.19M | buf1 4.19M | Whm 100.7M
  float*   memb   = (float*)ws;
  uint8_t* strain = ws + 16777216;
  uint8_t* buf0   = ws + 33554432;
  uint8_t* buf1   = ws + 37748736;
  uint8_t* Whm    = ws + 41943040;

  zero_f32_kernel<<<dim3(4096), 256, 0, stream>>>(memb, 1048576);
  zero_f32_kernel<<<dim3(512),  256, 0, stream>>>(out, 131072);
  spikes_kernel<<<dim3(128, 8), 256, 0, stream>>>(x, strain);
  for (int c = 0; c < NCORE; ++c)          // 8 slices
    wsplit_kernel<<<dim3(16, 32), 256, 0, stream>>>(W, Whm, c);

  for (int t = 0; t < NSTEP; ++t) {
    int c_lo = (t > TSIM - 1) ? (t - (TSIM - 1)) : 0;
    int c_hi = (t < NCORE - 1) ? t : (NCORE - 1);
    int nc = c_hi - c_lo + 1;
    uint8_t* prev = (t & 1) ? buf0 : buf1;
    uint8_t* cur  = (t & 1) ? buf1 : buf0;
    if (nc <= 4) {
      step_kernel<32><<<dim3(nc, 64), 512, 0, stream>>>(
          Whm, thr, strain, prev, cur, memb, out, t, c_lo);
    } else {
      step_kernel<64><<<dim3(nc, 32), 512, 0, stream>>>(
          Whm, thr, strain, prev, cur, memb, out, t, c_lo);
    }
  }
}